// Round 1
// baseline (342.608 us; speedup 1.0000x reference)
//
#include <hip/hip_runtime.h>
#include <hip/hip_bf16.h>
#include <stdint.h>

#define B_ 4
#define T_ 2048
#define D_ 1024
#define H_ 16
#define HD_ 64
#define M_TOT (B_ * T_)   // 8192

typedef unsigned short u16t;
typedef __bf16 bf16x8 __attribute__((ext_vector_type(8)));
typedef float f32x4 __attribute__((ext_vector_type(4)));

__device__ __forceinline__ u16t f2bf(float f) {
    union { float f; uint32_t u; } x; x.f = f;
    uint32_t r = x.u + 0x7fffu + ((x.u >> 16) & 1u);
    return (u16t)(r >> 16);
}

// ---------------- convert x (fp32 -> bf16), 8 elems/thread ----------------
__global__ __launch_bounds__(256) void cvt_bf16_kernel(const float* __restrict__ in,
                                                       u16t* __restrict__ out, int n8) {
    int i = blockIdx.x * 256 + threadIdx.x;
    if (i >= n8) return;
    const float4* p = (const float4*)in + (size_t)i * 2;
    float4 a = p[0], b = p[1];
    u16t o[8] = {f2bf(a.x), f2bf(a.y), f2bf(a.z), f2bf(a.w),
                 f2bf(b.x), f2bf(b.y), f2bf(b.z), f2bf(b.w)};
    *(uint4*)(out + (size_t)i * 8) = *(const uint4*)o;
}

// ------------- transpose + convert W[k][n] fp32 -> Wt[n][k] bf16 -------------
__global__ __launch_bounds__(256) void transp_kernel(const float* __restrict__ W0,
                                                     const float* __restrict__ W1,
                                                     const float* __restrict__ W2,
                                                     const float* __restrict__ W3,
                                                     u16t* __restrict__ T0,
                                                     u16t* __restrict__ T1,
                                                     u16t* __restrict__ T2,
                                                     u16t* __restrict__ T3) {
    __shared__ u16t tile[64][65];
    const float* W; u16t* To;
    switch (blockIdx.z) {
        case 0: W = W0; To = T0; break;
        case 1: W = W1; To = T1; break;
        case 2: W = W2; To = T2; break;
        default: W = W3; To = T3; break;
    }
    int n0 = blockIdx.x * 64, k0 = blockIdx.y * 64;
    int t = threadIdx.x;
#pragma unroll
    for (int i = 0; i < 16; ++i) {
        int idx = i * 256 + t;
        int r = idx >> 6, c = idx & 63;
        tile[r][c] = f2bf(W[(size_t)(k0 + r) * D_ + n0 + c]);
    }
    __syncthreads();
#pragma unroll
    for (int i = 0; i < 16; ++i) {
        int idx = i * 256 + t;
        int r = idx >> 6, c = idx & 63;
        To[(size_t)(n0 + r) * D_ + k0 + c] = tile[c][r];
    }
}

// ---------------- bf16 GEMM: C[M,N] = (A[M,K] @ Wt[N,K]^T + bias) * scale ----------------
// 128x128 tile, BK=64, 256 threads = 4 waves (2x2), each wave 64x64 out.
template <int F32OUT>
__global__ __launch_bounds__(256) void gemm_bf16_kernel(const u16t* __restrict__ A,
                                                        const u16t* __restrict__ Wt,
                                                        const float* __restrict__ bias,
                                                        void* __restrict__ outp,
                                                        float scale, int M, int N, int K) {
    __shared__ u16t As[128][72];
    __shared__ u16t Bs[128][72];
    const int t = threadIdx.x;
    const int lane = t & 63, w = t >> 6;
    const int wm = w >> 1, wn = w & 1;
    const int l15 = lane & 15, l4 = lane >> 4;
    const int m0 = blockIdx.x * 128, n0 = blockIdx.y * 128;

    f32x4 acc[4][4] = {};

    for (int k0 = 0; k0 < K; k0 += 64) {
        __syncthreads();
#pragma unroll
        for (int i = 0; i < 4; ++i) {
            int chunk = i * 256 + t;
            int r = chunk >> 3, c = (chunk & 7) * 8;
            *(uint4*)&As[r][c] = *(const uint4*)&A[(size_t)(m0 + r) * K + k0 + c];
            *(uint4*)&Bs[r][c] = *(const uint4*)&Wt[(size_t)(n0 + r) * K + k0 + c];
        }
        __syncthreads();
#pragma unroll
        for (int ks = 0; ks < 64; ks += 32) {
            bf16x8 af[4], bf[4];
#pragma unroll
            for (int i = 0; i < 4; ++i) {
                af[i] = *(const bf16x8*)&As[wm * 64 + i * 16 + l15][ks + l4 * 8];
                bf[i] = *(const bf16x8*)&Bs[wn * 64 + i * 16 + l15][ks + l4 * 8];
            }
#pragma unroll
            for (int mi = 0; mi < 4; ++mi)
#pragma unroll
                for (int ni = 0; ni < 4; ++ni)
                    acc[mi][ni] = __builtin_amdgcn_mfma_f32_16x16x32_bf16(
                        af[mi], bf[ni], acc[mi][ni], 0, 0, 0);
        }
    }

    // epilogue: D frag layout col = lane&15, row = (lane>>4)*4 + reg
#pragma unroll
    for (int mi = 0; mi < 4; ++mi) {
#pragma unroll
        for (int ni = 0; ni < 4; ++ni) {
            int col = n0 + wn * 64 + ni * 16 + l15;
            float bn = bias[col];
#pragma unroll
            for (int r = 0; r < 4; ++r) {
                int row = m0 + wm * 64 + mi * 16 + l4 * 4 + r;
                float v = (acc[mi][ni][r] + bn) * scale;
                if (F32OUT)
                    ((float*)outp)[(size_t)row * N + col] = v;
                else
                    ((u16t*)outp)[(size_t)row * N + col] = f2bf(v);
            }
        }
    }
}

// ---------------- causal flash attention ----------------
// grid: (T/64, B*H); block 256 = 4 waves; wave w handles q rows [q0+16w, q0+16w+16)
__global__ __launch_bounds__(256) void attn_kernel(const u16t* __restrict__ Q,
                                                   const u16t* __restrict__ K,
                                                   const u16t* __restrict__ V,
                                                   u16t* __restrict__ O) {
    __shared__ u16t Ks[64][72];
    __shared__ u16t Vs[64][72];
    __shared__ u16t Ps[4][16][72];

    const int t = threadIdx.x;
    const int lane = t & 63, w = t >> 6;
    const int l15 = lane & 15, l4 = lane >> 4;
    const int qt = blockIdx.x;
    const int bh = blockIdx.y;
    const int b = bh >> 4, h = bh & 15;
    const size_t base = (size_t)b * T_ * D_ + (size_t)h * HD_;
    const int q0 = qt * 64;
    const int qrow = q0 + w * 16 + l15;  // this lane's q column in S^T

    // Q fragments (B operand of swapped mfma): lane holds Q[q=l15][d=l4*8+j]
    bf16x8 qf0 = *(const bf16x8*)&Q[base + (size_t)(q0 + w * 16 + l15) * D_ + l4 * 8];
    bf16x8 qf1 = *(const bf16x8*)&Q[base + (size_t)(q0 + w * 16 + l15) * D_ + 32 + l4 * 8];

    f32x4 acc_o[4] = {};   // O[q' = l4*4+reg][d = l15 + 16*nt]
    float mrun = -1e30f, lrun = 0.f;

    for (int jt = 0; jt <= qt; ++jt) {
        const int kv0 = jt * 64;
        __syncthreads();
#pragma unroll
        for (int i = 0; i < 2; ++i) {
            int chunk = i * 256 + t;
            int r = chunk >> 3, c = (chunk & 7) * 8;
            *(uint4*)&Ks[r][c] = *(const uint4*)&K[base + (size_t)(kv0 + r) * D_ + c];
            *(uint4*)&Vs[r][c] = *(const uint4*)&V[base + (size_t)(kv0 + r) * D_ + c];
        }
        __syncthreads();

        // S^T = K * Q^T : accs[mt] holds rows kv = 16*mt + l4*4+reg, col q=l15
        f32x4 accs[4] = {};
#pragma unroll
        for (int mt = 0; mt < 4; ++mt) {
            bf16x8 kf0 = *(const bf16x8*)&Ks[mt * 16 + l15][l4 * 8];
            bf16x8 kf1 = *(const bf16x8*)&Ks[mt * 16 + l15][32 + l4 * 8];
            accs[mt] = __builtin_amdgcn_mfma_f32_16x16x32_bf16(kf0, qf0, accs[mt], 0, 0, 0);
            accs[mt] = __builtin_amdgcn_mfma_f32_16x16x32_bf16(kf1, qf1, accs[mt], 0, 0, 0);
        }

        if (jt == qt) {  // diagonal tile: causal mask
#pragma unroll
            for (int mt = 0; mt < 4; ++mt)
#pragma unroll
                for (int r = 0; r < 4; ++r) {
                    int kv = kv0 + mt * 16 + l4 * 4 + r;
                    if (kv > qrow) accs[mt][r] = -1e30f;
                }
        }

        // row max over kv for q = l15 (16 in-lane + lanes xor16, xor32)
        float pmax = -1e30f;
#pragma unroll
        for (int mt = 0; mt < 4; ++mt)
#pragma unroll
            for (int r = 0; r < 4; ++r) pmax = fmaxf(pmax, accs[mt][r]);
        pmax = fmaxf(pmax, __shfl_xor(pmax, 16));
        pmax = fmaxf(pmax, __shfl_xor(pmax, 32));

        float mnew = fmaxf(mrun, pmax);
        float corr = __expf(mrun - mnew);

        float psum = 0.f;
        u16t pb[4][4];
#pragma unroll
        for (int mt = 0; mt < 4; ++mt)
#pragma unroll
            for (int r = 0; r < 4; ++r) {
                float p = __expf(accs[mt][r] - mnew);
                psum += p;
                pb[mt][r] = f2bf(p);
            }
        psum += __shfl_xor(psum, 16);
        psum += __shfl_xor(psum, 32);
        lrun = lrun * corr + psum;
        mrun = mnew;

        // write P^T values into per-wave P tile as P[q][kv]
#pragma unroll
        for (int mt = 0; mt < 4; ++mt)
#pragma unroll
            for (int r = 0; r < 4; ++r)
                Ps[w][l15][mt * 16 + l4 * 4 + r] = pb[mt][r];

        // rescale O rows (row q' = l4*4 + reg; corr lives in lane q')
#pragma unroll
        for (int r = 0; r < 4; ++r) {
            float f = __shfl(corr, l4 * 4 + r);
#pragma unroll
            for (int nt = 0; nt < 4; ++nt) acc_o[nt][r] *= f;
        }

        // PV: O += P[16q x 64kv] @ V[64kv x 64d]
#pragma unroll
        for (int ks = 0; ks < 2; ++ks) {
            bf16x8 pf = *(const bf16x8*)&Ps[w][l15][ks * 32 + l4 * 8];
#pragma unroll
            for (int nt = 0; nt < 4; ++nt) {
                bf16x8 vf;
#pragma unroll
                for (int j = 0; j < 8; ++j)
                    ((__bf16*)&vf)[j] = *(const __bf16*)&Vs[ks * 32 + l4 * 8 + j][nt * 16 + l15];
                acc_o[nt] = __builtin_amdgcn_mfma_f32_16x16x32_bf16(pf, vf, acc_o[nt], 0, 0, 0);
            }
        }
    }

    // finalize: divide by l, store bf16
#pragma unroll
    for (int r = 0; r < 4; ++r) {
        float li = __shfl(lrun, l4 * 4 + r);
        float inv = 1.f / li;
        int row = q0 + w * 16 + l4 * 4 + r;
#pragma unroll
        for (int nt = 0; nt < 4; ++nt)
            O[base + (size_t)row * D_ + nt * 16 + l15] = f2bf(acc_o[nt][r] * inv);
    }
}

extern "C" void kernel_launch(void* const* d_in, const int* in_sizes, int n_in,
                              void* d_out, int out_size, void* d_ws, size_t ws_size,
                              hipStream_t stream) {
    const float* x  = (const float*)d_in[0];
    const float* Wq = (const float*)d_in[1];
    const float* bq = (const float*)d_in[2];
    const float* Wk = (const float*)d_in[3];
    const float* bk = (const float*)d_in[4];
    const float* Wv = (const float*)d_in[5];
    const float* bv = (const float*)d_in[6];
    const float* Wp = (const float*)d_in[7];
    const float* bp = (const float*)d_in[8];
    float* out = (float*)d_out;

    // workspace layout (bf16 elements)
    u16t* ws = (u16t*)d_ws;
    const size_t XN = (size_t)M_TOT * D_;      // 8M elems
    u16t* xb  = ws;                            // [8192][1024]
    u16t* q   = ws + XN;                       // [8192][1024]
    u16t* k   = ws + 2 * XN;
    u16t* v   = ws + 3 * XN;
    u16t* wtq = ws + 4 * XN;                   // [1024][1024] each
    u16t* wtk = wtq + (size_t)D_ * D_;
    u16t* wtv = wtk + (size_t)D_ * D_;
    u16t* wtp = wtv + (size_t)D_ * D_;
    u16t* o   = xb;                            // reuse xb after QKV GEMMs

    cvt_bf16_kernel<<<(int)(XN / 8 / 256), 256, 0, stream>>>(x, xb, (int)(XN / 8));
    transp_kernel<<<dim3(16, 16, 4), 256, 0, stream>>>(Wq, Wk, Wv, Wp, wtq, wtk, wtv, wtp);

    dim3 ggrid(M_TOT / 128, D_ / 128);
    gemm_bf16_kernel<0><<<ggrid, 256, 0, stream>>>(xb, wtq, bq, q, 0.125f, M_TOT, D_, D_);
    gemm_bf16_kernel<0><<<ggrid, 256, 0, stream>>>(xb, wtk, bk, k, 1.0f, M_TOT, D_, D_);
    gemm_bf16_kernel<0><<<ggrid, 256, 0, stream>>>(xb, wtv, bv, v, 1.0f, M_TOT, D_, D_);

    attn_kernel<<<dim3(T_ / 64, B_ * H_), 256, 0, stream>>>(q, k, v, o);

    gemm_bf16_kernel<1><<<ggrid, 256, 0, stream>>>(o, wtp, bp, out, 1.0f, M_TOT, D_, D_);
}

// Round 2
// 328.086 us; speedup vs baseline: 1.0443x; 1.0443x over previous
//
#include <hip/hip_runtime.h>
#include <hip/hip_bf16.h>
#include <stdint.h>

#define B_ 4
#define T_ 2048
#define D_ 1024
#define H_ 16
#define HD_ 64
#define M_TOT (B_ * T_)   // 8192

typedef unsigned short u16t;
typedef __bf16 bf16x8 __attribute__((ext_vector_type(8)));
typedef float f32x4 __attribute__((ext_vector_type(4)));

__device__ __forceinline__ u16t f2bf(float f) {
    union { float f; uint32_t u; } x; x.f = f;
    uint32_t r = x.u + 0x7fffu + ((x.u >> 16) & 1u);
    return (u16t)(r >> 16);
}

// ---------------- convert x (fp32 -> bf16), 8 elems/thread ----------------
__global__ __launch_bounds__(256) void cvt_bf16_kernel(const float* __restrict__ in,
                                                       u16t* __restrict__ out, int n8) {
    int i = blockIdx.x * 256 + threadIdx.x;
    if (i >= n8) return;
    const float4* p = (const float4*)in + (size_t)i * 2;
    float4 a = p[0], b = p[1];
    u16t o[8] = {f2bf(a.x), f2bf(a.y), f2bf(a.z), f2bf(a.w),
                 f2bf(b.x), f2bf(b.y), f2bf(b.z), f2bf(b.w)};
    *(uint4*)(out + (size_t)i * 8) = *(const uint4*)o;
}

// ------------- transpose + convert W[k][n] fp32 -> Wt[n][k] bf16 -------------
__global__ __launch_bounds__(256) void transp_kernel(const float* __restrict__ W0,
                                                     const float* __restrict__ W1,
                                                     const float* __restrict__ W2,
                                                     const float* __restrict__ W3,
                                                     u16t* __restrict__ T0,
                                                     u16t* __restrict__ T1,
                                                     u16t* __restrict__ T2,
                                                     u16t* __restrict__ T3) {
    __shared__ u16t tile[64][65];
    const float* W; u16t* To;
    switch (blockIdx.z) {
        case 0: W = W0; To = T0; break;
        case 1: W = W1; To = T1; break;
        case 2: W = W2; To = T2; break;
        default: W = W3; To = T3; break;
    }
    int n0 = blockIdx.x * 64, k0 = blockIdx.y * 64;
    int t = threadIdx.x;
#pragma unroll
    for (int i = 0; i < 16; ++i) {
        int idx = i * 256 + t;
        int r = idx >> 6, c = idx & 63;
        tile[r][c] = f2bf(W[(size_t)(k0 + r) * D_ + n0 + c]);
    }
    __syncthreads();
#pragma unroll
    for (int i = 0; i < 16; ++i) {
        int idx = i * 256 + t;
        int r = idx >> 6, c = idx & 63;
        To[(size_t)(n0 + r) * D_ + k0 + c] = tile[c][r];
    }
}

// ------------- transpose V bf16 [B*T][D] -> Vt[b][h][d][t] -------------
__global__ __launch_bounds__(256) void transp_v_kernel(const u16t* __restrict__ v,
                                                       u16t* __restrict__ vt) {
    __shared__ u16t tile[64][68];   // pad 68: ~2-4 way conflicts max
    const int t = threadIdx.x;
    const int bh = blockIdx.y;
    const int b = bh >> 4, h = bh & 15;
    const int t0 = blockIdx.x * 64;
#pragma unroll
    for (int i = 0; i < 2; ++i) {
        int chunk = i * 256 + t;
        int r = chunk >> 3, c = (chunk & 7) * 8;
        uint4 d4 = *(const uint4*)&v[(size_t)(b * T_ + t0 + r) * D_ + h * 64 + c];
        *(uint2*)&tile[r][c]     = make_uint2(d4.x, d4.y);
        *(uint2*)&tile[r][c + 4] = make_uint2(d4.z, d4.w);
    }
    __syncthreads();
#pragma unroll
    for (int i = 0; i < 2; ++i) {
        int chunk = i * 256 + t;
        int d = chunk >> 3, ts = (chunk & 7) * 8;
        u16t o[8];
#pragma unroll
        for (int j = 0; j < 8; ++j) o[j] = tile[ts + j][d];
        *(uint4*)&vt[((size_t)bh * HD_ + d) * T_ + t0 + ts] = *(const uint4*)o;
    }
}

// ---------------- bf16 GEMM: C[M,N] = (A[M,K] @ Wt[N,K]^T + bias) * scale ----------------
template <int F32OUT>
__global__ __launch_bounds__(256) void gemm_bf16_kernel(const u16t* __restrict__ A,
                                                        const u16t* __restrict__ Wt,
                                                        const float* __restrict__ bias,
                                                        void* __restrict__ outp,
                                                        float scale, int M, int N, int K) {
    __shared__ u16t As[128][72];
    __shared__ u16t Bs[128][72];
    const int t = threadIdx.x;
    const int lane = t & 63, w = t >> 6;
    const int wm = w >> 1, wn = w & 1;
    const int l15 = lane & 15, l4 = lane >> 4;
    const int m0 = blockIdx.x * 128, n0 = blockIdx.y * 128;

    f32x4 acc[4][4] = {};

    for (int k0 = 0; k0 < K; k0 += 64) {
        __syncthreads();
#pragma unroll
        for (int i = 0; i < 4; ++i) {
            int chunk = i * 256 + t;
            int r = chunk >> 3, c = (chunk & 7) * 8;
            *(uint4*)&As[r][c] = *(const uint4*)&A[(size_t)(m0 + r) * K + k0 + c];
            *(uint4*)&Bs[r][c] = *(const uint4*)&Wt[(size_t)(n0 + r) * K + k0 + c];
        }
        __syncthreads();
#pragma unroll
        for (int ks = 0; ks < 64; ks += 32) {
            bf16x8 af[4], bf[4];
#pragma unroll
            for (int i = 0; i < 4; ++i) {
                af[i] = *(const bf16x8*)&As[wm * 64 + i * 16 + l15][ks + l4 * 8];
                bf[i] = *(const bf16x8*)&Bs[wn * 64 + i * 16 + l15][ks + l4 * 8];
            }
#pragma unroll
            for (int mi = 0; mi < 4; ++mi)
#pragma unroll
                for (int ni = 0; ni < 4; ++ni)
                    acc[mi][ni] = __builtin_amdgcn_mfma_f32_16x16x32_bf16(
                        af[mi], bf[ni], acc[mi][ni], 0, 0, 0);
        }
    }

#pragma unroll
    for (int mi = 0; mi < 4; ++mi) {
#pragma unroll
        for (int ni = 0; ni < 4; ++ni) {
            int col = n0 + wn * 64 + ni * 16 + l15;
            float bn = bias[col];
#pragma unroll
            for (int r = 0; r < 4; ++r) {
                int row = m0 + wm * 64 + mi * 16 + l4 * 4 + r;
                float v = (acc[mi][ni][r] + bn) * scale;
                if (F32OUT)
                    ((float*)outp)[(size_t)row * N + col] = v;
                else
                    ((u16t*)outp)[(size_t)row * N + col] = f2bf(v);
            }
        }
    }
}

// ---------------- causal flash attention ----------------
// grid: (T/128, B*H); block 256 = 4 waves; wave w owns q rows [q0+32w, q0+32w+32)
// V is consumed pre-transposed (Vt[b][h][d][t]) so all LDS reads are ds_read_b128.
__global__ __launch_bounds__(256, 4) void attn_kernel(const u16t* __restrict__ Q,
                                                      const u16t* __restrict__ K,
                                                      const u16t* __restrict__ Vt,
                                                      u16t* __restrict__ O) {
    __shared__ u16t Ks[64][72];
    __shared__ u16t Vs[64][72];     // transposed: Vs[d][kv]
    __shared__ u16t Ps[4][32][72];  // per-wave P[q][kv], col XOR-swizzled

    const int t = threadIdx.x;
    const int lane = t & 63, w = t >> 6;
    const int l15 = lane & 15, l4 = lane >> 4;
    const int qtile = gridDim.x - 1 - blockIdx.x;  // heavy blocks dispatch first
    const int bh = blockIdx.y;
    const size_t base = (size_t)(bh >> 4) * T_ * D_ + (size_t)(bh & 15) * HD_;
    const size_t vtbase = (size_t)bh * HD_ * T_;
    const int q0 = qtile * 128;
    const int qsub0 = q0 + w * 32;
    const int swz = (l15 & 3) << 3;

    bf16x8 qf[2][2];
#pragma unroll
    for (int qa = 0; qa < 2; ++qa) {
        const u16t* qp = &Q[base + (size_t)(qsub0 + qa * 16 + l15) * D_];
        qf[qa][0] = *(const bf16x8*)&qp[l4 * 8];
        qf[qa][1] = *(const bf16x8*)&qp[32 + l4 * 8];
    }

    f32x4 acc_o[2][4] = {};  // [qa][nt], rows q' = l4*4+r, cols d = nt*16+l15
    float mrun[2] = {-1e30f, -1e30f};
    float lrun[2] = {0.f, 0.f};

    const int njt = 2 * qtile + 2;
    for (int jt = 0; jt < njt; ++jt) {
        const int kv0 = jt * 64;
        __syncthreads();
#pragma unroll
        for (int i = 0; i < 2; ++i) {
            int chunk = i * 256 + t;
            int r = chunk >> 3, c = (chunk & 7) * 8;
            *(uint4*)&Ks[r][c] = *(const uint4*)&K[base + (size_t)(kv0 + r) * D_ + c];
            *(uint4*)&Vs[r][c] = *(const uint4*)&Vt[vtbase + (size_t)r * T_ + kv0 + c];
        }
        __syncthreads();

        // S^T = K * Q^T : accs[qa][mt] rows kv = mt*16 + l4*4+r, col q = l15
        f32x4 accs[2][4] = {};
#pragma unroll
        for (int mt = 0; mt < 4; ++mt) {
            bf16x8 kf0 = *(const bf16x8*)&Ks[mt * 16 + l15][l4 * 8];
            bf16x8 kf1 = *(const bf16x8*)&Ks[mt * 16 + l15][32 + l4 * 8];
            accs[0][mt] = __builtin_amdgcn_mfma_f32_16x16x32_bf16(kf0, qf[0][0], accs[0][mt], 0, 0, 0);
            accs[0][mt] = __builtin_amdgcn_mfma_f32_16x16x32_bf16(kf1, qf[0][1], accs[0][mt], 0, 0, 0);
            accs[1][mt] = __builtin_amdgcn_mfma_f32_16x16x32_bf16(kf0, qf[1][0], accs[1][mt], 0, 0, 0);
            accs[1][mt] = __builtin_amdgcn_mfma_f32_16x16x32_bf16(kf1, qf[1][1], accs[1][mt], 0, 0, 0);
        }

#pragma unroll
        for (int qa = 0; qa < 2; ++qa) {
            const int qrow = qsub0 + qa * 16 + l15;
            if (kv0 + 63 > qsub0 + qa * 16) {  // tile touches/passes diagonal: mask
#pragma unroll
                for (int mt = 0; mt < 4; ++mt)
#pragma unroll
                    for (int r = 0; r < 4; ++r)
                        if (kv0 + mt * 16 + l4 * 4 + r > qrow) accs[qa][mt][r] = -1e30f;
            }

            float pmax = -1e30f;
#pragma unroll
            for (int mt = 0; mt < 4; ++mt)
#pragma unroll
                for (int r = 0; r < 4; ++r) pmax = fmaxf(pmax, accs[qa][mt][r]);
            pmax = fmaxf(pmax, __shfl_xor(pmax, 16));
            pmax = fmaxf(pmax, __shfl_xor(pmax, 32));

            float mnew = fmaxf(mrun[qa], pmax);
            float corr = __expf(mrun[qa] - mnew);

            float psum = 0.f;
#pragma unroll
            for (int mt = 0; mt < 4; ++mt)
#pragma unroll
                for (int r = 0; r < 4; ++r) {
                    float p = __expf(accs[qa][mt][r] - mnew);
                    psum += p;
                    Ps[w][qa * 16 + l15][(mt * 16 + l4 * 4 + r) ^ swz] = f2bf(p);
                }
            psum += __shfl_xor(psum, 16);
            psum += __shfl_xor(psum, 32);
            lrun[qa] = lrun[qa] * corr + psum;
            mrun[qa] = mnew;

#pragma unroll
            for (int r = 0; r < 4; ++r) {
                float f = __shfl(corr, l4 * 4 + r);
#pragma unroll
                for (int nt = 0; nt < 4; ++nt) acc_o[qa][nt][r] *= f;
            }
        }

        // PV: O[qa] += P[qa] @ V   (vf shared across both q-subtiles)
#pragma unroll
        for (int ks = 0; ks < 2; ++ks) {
            bf16x8 pfa = *(const bf16x8*)&Ps[w][l15][(ks * 32 + l4 * 8) ^ swz];
            bf16x8 pfb = *(const bf16x8*)&Ps[w][16 + l15][(ks * 32 + l4 * 8) ^ swz];
#pragma unroll
            for (int nt = 0; nt < 4; ++nt) {
                bf16x8 vf = *(const bf16x8*)&Vs[nt * 16 + l15][ks * 32 + l4 * 8];
                acc_o[0][nt] = __builtin_amdgcn_mfma_f32_16x16x32_bf16(pfa, vf, acc_o[0][nt], 0, 0, 0);
                acc_o[1][nt] = __builtin_amdgcn_mfma_f32_16x16x32_bf16(pfb, vf, acc_o[1][nt], 0, 0, 0);
            }
        }
    }

    // finalize: divide by l, store bf16
#pragma unroll
    for (int qa = 0; qa < 2; ++qa)
#pragma unroll
        for (int r = 0; r < 4; ++r) {
            float li = __shfl(lrun[qa], l4 * 4 + r);
            float inv = 1.f / li;
            int row = qsub0 + qa * 16 + l4 * 4 + r;
#pragma unroll
            for (int nt = 0; nt < 4; ++nt)
                O[base + (size_t)row * D_ + nt * 16 + l15] = f2bf(acc_o[qa][nt][r] * inv);
        }
}

extern "C" void kernel_launch(void* const* d_in, const int* in_sizes, int n_in,
                              void* d_out, int out_size, void* d_ws, size_t ws_size,
                              hipStream_t stream) {
    const float* x  = (const float*)d_in[0];
    const float* Wq = (const float*)d_in[1];
    const float* bq = (const float*)d_in[2];
    const float* Wk = (const float*)d_in[3];
    const float* bk = (const float*)d_in[4];
    const float* Wv = (const float*)d_in[5];
    const float* bv = (const float*)d_in[6];
    const float* Wp = (const float*)d_in[7];
    const float* bp = (const float*)d_in[8];
    float* out = (float*)d_out;

    // workspace layout (bf16 elements); total = 4*XN + 4*D^2 elems = 72 MB
    u16t* ws = (u16t*)d_ws;
    const size_t XN = (size_t)M_TOT * D_;      // 8M elems
    u16t* xb  = ws;                            // [8192][1024]; reused as Vt after QKV
    u16t* q   = ws + XN;
    u16t* k   = ws + 2 * XN;
    u16t* v   = ws + 3 * XN;                   // reused as attn output O after transp_v
    u16t* wtq = ws + 4 * XN;
    u16t* wtk = wtq + (size_t)D_ * D_;
    u16t* wtv = wtk + (size_t)D_ * D_;
    u16t* wtp = wtv + (size_t)D_ * D_;
    u16t* vt  = xb;                            // Vt[b][h][d][t]
    u16t* o   = v;                             // attn output

    cvt_bf16_kernel<<<(int)(XN / 8 / 256), 256, 0, stream>>>(x, xb, (int)(XN / 8));
    transp_kernel<<<dim3(16, 16, 4), 256, 0, stream>>>(Wq, Wk, Wv, Wp, wtq, wtk, wtv, wtp);

    dim3 ggrid(M_TOT / 128, D_ / 128);
    gemm_bf16_kernel<0><<<ggrid, 256, 0, stream>>>(xb, wtq, bq, q, 0.125f, M_TOT, D_, D_);
    gemm_bf16_kernel<0><<<ggrid, 256, 0, stream>>>(xb, wtk, bk, k, 1.0f, M_TOT, D_, D_);
    gemm_bf16_kernel<0><<<ggrid, 256, 0, stream>>>(xb, wtv, bv, v, 1.0f, M_TOT, D_, D_);

    // xb dead from here; v dead after transp_v
    transp_v_kernel<<<dim3(T_ / 64, B_ * H_), 256, 0, stream>>>(v, vt);

    attn_kernel<<<dim3(T_ / 128, B_ * H_), 256, 0, stream>>>(q, k, vt, o);

    gemm_bf16_kernel<1><<<ggrid, 256, 0, stream>>>(o, wtp, bp, out, 1.0f, M_TOT, D_, D_);
}

// Round 3
// 285.631 us; speedup vs baseline: 1.1995x; 1.1486x over previous
//
#include <hip/hip_runtime.h>
#include <hip/hip_bf16.h>
#include <stdint.h>

#define B_ 4
#define T_ 2048
#define D_ 1024
#define H_ 16
#define HD_ 64
#define M_TOT (B_ * T_)   // 8192

typedef unsigned short u16t;
typedef __bf16 bf16x4 __attribute__((ext_vector_type(4)));
typedef __bf16 bf16x8 __attribute__((ext_vector_type(8)));
typedef float f32x4 __attribute__((ext_vector_type(4)));

__device__ __forceinline__ u16t f2bf(float f) {
    union { float f; uint32_t u; } x; x.f = f;
    uint32_t r = x.u + 0x7fffu + ((x.u >> 16) & 1u);
    return (u16t)(r >> 16);
}

// async global -> LDS, 16B per lane; lds dest must be wave-uniform base (+ lane*16 by HW)
__device__ __forceinline__ void gload16(const void* g, void* l) {
    __builtin_amdgcn_global_load_lds((const __attribute__((address_space(1))) void*)g,
                                     (__attribute__((address_space(3))) void*)l, 16, 0, 0);
}

// ---------------- convert x (fp32 -> bf16), 8 elems/thread ----------------
__global__ __launch_bounds__(256) void cvt_bf16_kernel(const float* __restrict__ in,
                                                       u16t* __restrict__ out, int n8) {
    int i = blockIdx.x * 256 + threadIdx.x;
    if (i >= n8) return;
    const float4* p = (const float4*)in + (size_t)i * 2;
    float4 a = p[0], b = p[1];
    u16t o[8] = {f2bf(a.x), f2bf(a.y), f2bf(a.z), f2bf(a.w),
                 f2bf(b.x), f2bf(b.y), f2bf(b.z), f2bf(b.w)};
    *(uint4*)(out + (size_t)i * 8) = *(const uint4*)o;
}

// ------------- transpose + convert W[k][n] fp32 -> Wt[n][k] bf16 -------------
__global__ __launch_bounds__(256) void transp_kernel(const float* __restrict__ W0,
                                                     const float* __restrict__ W1,
                                                     const float* __restrict__ W2,
                                                     const float* __restrict__ W3,
                                                     u16t* __restrict__ T0,
                                                     u16t* __restrict__ T1,
                                                     u16t* __restrict__ T2,
                                                     u16t* __restrict__ T3) {
    __shared__ u16t tile[64][65];
    const float* W; u16t* To;
    switch (blockIdx.z) {
        case 0: W = W0; To = T0; break;
        case 1: W = W1; To = T1; break;
        case 2: W = W2; To = T2; break;
        default: W = W3; To = T3; break;
    }
    int n0 = blockIdx.x * 64, k0 = blockIdx.y * 64;
    int t = threadIdx.x;
#pragma unroll
    for (int i = 0; i < 16; ++i) {
        int idx = i * 256 + t;
        int r = idx >> 6, c = idx & 63;
        tile[r][c] = f2bf(W[(size_t)(k0 + r) * D_ + n0 + c]);
    }
    __syncthreads();
#pragma unroll
    for (int i = 0; i < 16; ++i) {
        int idx = i * 256 + t;
        int r = idx >> 6, c = idx & 63;
        To[(size_t)(n0 + r) * D_ + k0 + c] = tile[c][r];
    }
}

// ---------------- bf16 GEMM (m97 structure: global_load_lds staging, linear LDS) ----
// MODE 0: bf16 row-major out. MODE 1: f32 row-major out. MODE 2: bf16 Vt[b][h][hd][t] out.
template <int MODE>
__global__ __launch_bounds__(256) void gemm_bf16_kernel(const u16t* __restrict__ A,
                                                        const u16t* __restrict__ Wt,
                                                        const float* __restrict__ bias,
                                                        void* __restrict__ outp,
                                                        float scale) {
    __shared__ u16t As[128 * 64];
    __shared__ u16t Bs[128 * 64];
    const int t = threadIdx.x;
    const int lane = t & 63, w = t >> 6;
    const int wm = w >> 1, wn = w & 1;
    const int l15 = lane & 15, l4 = lane >> 4;
    const int m0 = blockIdx.x * 128, n0 = blockIdx.y * 128;
    const int K = D_, N = D_;

    f32x4 acc[4][4] = {};

    for (int k0 = 0; k0 < K; k0 += 64) {
#pragma unroll
        for (int i = 0; i < 4; ++i) {
            int lin = i * 256 + t;
            int r = lin >> 3, c = (lin & 7) * 8;
            int ldsoff = (i * 256 + w * 64) * 8;   // wave-uniform, u16 units
            gload16(&A[(size_t)(m0 + r) * K + k0 + c], &As[ldsoff]);
            gload16(&Wt[(size_t)(n0 + r) * K + k0 + c], &Bs[ldsoff]);
        }
        __syncthreads();   // drains vmcnt -> staged data visible
#pragma unroll
        for (int ks = 0; ks < 64; ks += 32) {
            bf16x8 af[4], bf[4];
#pragma unroll
            for (int i = 0; i < 4; ++i) {
                af[i] = *(const bf16x8*)&As[(wm * 64 + i * 16 + l15) * 64 + ks + l4 * 8];
                bf[i] = *(const bf16x8*)&Bs[(wn * 64 + i * 16 + l15) * 64 + ks + l4 * 8];
            }
#pragma unroll
            for (int mi = 0; mi < 4; ++mi)
#pragma unroll
                for (int ni = 0; ni < 4; ++ni)
                    acc[mi][ni] = __builtin_amdgcn_mfma_f32_16x16x32_bf16(
                        af[mi], bf[ni], acc[mi][ni], 0, 0, 0);
        }
        __syncthreads();
    }

#pragma unroll
    for (int mi = 0; mi < 4; ++mi) {
#pragma unroll
        for (int ni = 0; ni < 4; ++ni) {
            int col = n0 + wn * 64 + ni * 16 + l15;
            float bn = bias[col];
            if (MODE == 2) {
                int token0 = m0 + wm * 64 + mi * 16 + l4 * 4;
                u16t o4[4];
#pragma unroll
                for (int r = 0; r < 4; ++r) o4[r] = f2bf(acc[mi][ni][r] + bn);
                int b = token0 >> 11, tb = token0 & (T_ - 1);
                int h = col >> 6, hd = col & 63;
                *(uint2*)&((u16t*)outp)[(((size_t)b * H_ + h) * HD_ + hd) * T_ + tb] =
                    *(const uint2*)o4;
            } else {
#pragma unroll
                for (int r = 0; r < 4; ++r) {
                    int row = m0 + wm * 64 + mi * 16 + l4 * 4 + r;
                    float v = (acc[mi][ni][r] + bn) * scale;
                    if (MODE == 1) ((float*)outp)[(size_t)row * N + col] = v;
                    else           ((u16t*)outp)[(size_t)row * N + col] = f2bf(v);
                }
            }
        }
    }
}

// ---------------- causal flash attention ----------------
// 1024 blocks; work-balanced mapping: residency class lin%256 gets qtiles {x,15-x,x,15-x}
// (uniform 68 tile-iters per CU). P stays in registers: kv->k-slot permutation
// pi_s(l4,j) = 32s + (j>=4?16:0) + l4*4 + (j&3) makes own S^T regs the PV A-fragment;
// V fragments are two ds_read_b64 with the matching permutation.
__global__ __launch_bounds__(256, 4) void attn_kernel(const u16t* __restrict__ Q,
                                                      const u16t* __restrict__ K,
                                                      const u16t* __restrict__ Vt,
                                                      u16t* __restrict__ O) {
    __shared__ u16t Ks[64][72];
    __shared__ u16t Vs[64][72];    // Vs[d][kv]

    const int t = threadIdx.x;
    const int lane = t & 63, w = t >> 6;
    const int l15 = lane & 15, l4 = lane >> 4;

    const int lin = blockIdx.y * 16 + blockIdx.x;
    const int kk = lin >> 8;
    const int jb = (lin >> 4) & 15, jx = lin & 15;
    const int bh = kk * 16 + jb;
    const int qtile = (kk & 1) ? (15 - jx) : jx;

    const size_t base = (size_t)(bh >> 4) * T_ * D_ + (size_t)(bh & 15) * HD_;
    const size_t vtbase = (size_t)bh * HD_ * T_;
    const int q0 = qtile * 128;
    const int qsub0 = q0 + w * 32;

    const int sr0 = t >> 3, sc = (t & 7) * 8;

    bf16x8 qf[2][2];
#pragma unroll
    for (int qa = 0; qa < 2; ++qa) {
        const u16t* qp = &Q[base + (size_t)(qsub0 + qa * 16 + l15) * D_];
        qf[qa][0] = *(const bf16x8*)&qp[l4 * 8];
        qf[qa][1] = *(const bf16x8*)&qp[32 + l4 * 8];
    }

    f32x4 acc_o[2][4] = {};
    float mrun[2] = {-1e30f, -1e30f};
    float lrun[2] = {0.f, 0.f};

    uint4 kreg[2], vreg[2];
    auto issue = [&](int kv0) {
#pragma unroll
        for (int i = 0; i < 2; ++i) {
            int r = sr0 + 32 * i;
            kreg[i] = *(const uint4*)&K[base + (size_t)(kv0 + r) * D_ + sc];
            vreg[i] = *(const uint4*)&Vt[vtbase + (size_t)r * T_ + kv0 + sc];
        }
    };

    const int njt = 2 * qtile + 2;
    issue(0);

    for (int jt = 0; jt < njt; ++jt) {
        const int kv0 = jt * 64;
        // write staged regs -> LDS (waits on last iteration's loads)
#pragma unroll
        for (int i = 0; i < 2; ++i) {
            int r = sr0 + 32 * i;
            *(uint4*)&Ks[r][sc] = kreg[i];
            *(uint4*)&Vs[r][sc] = vreg[i];
        }
        __syncthreads();
        if (jt + 1 < njt) issue(kv0 + 64);   // hide HBM latency under compute

        // S^T = K * Q^T : accs[qa][mt], rows kv = kv0 + mt*16 + l4*4 + r, col q = l15
        f32x4 accs[2][4] = {};
#pragma unroll
        for (int mt = 0; mt < 4; ++mt) {
            bf16x8 kf0 = *(const bf16x8*)&Ks[mt * 16 + l15][l4 * 8];
            bf16x8 kf1 = *(const bf16x8*)&Ks[mt * 16 + l15][32 + l4 * 8];
            accs[0][mt] = __builtin_amdgcn_mfma_f32_16x16x32_bf16(kf0, qf[0][0], accs[0][mt], 0, 0, 0);
            accs[0][mt] = __builtin_amdgcn_mfma_f32_16x16x32_bf16(kf1, qf[0][1], accs[0][mt], 0, 0, 0);
            accs[1][mt] = __builtin_amdgcn_mfma_f32_16x16x32_bf16(kf0, qf[1][0], accs[1][mt], 0, 0, 0);
            accs[1][mt] = __builtin_amdgcn_mfma_f32_16x16x32_bf16(kf1, qf[1][1], accs[1][mt], 0, 0, 0);
        }

        bf16x8 pa[2][2];
#pragma unroll
        for (int qa = 0; qa < 2; ++qa) {
            const int qrow = qsub0 + qa * 16 + l15;
            if (kv0 + 63 > qsub0 + qa * 16) {   // diagonal-touching: causal mask
#pragma unroll
                for (int mt = 0; mt < 4; ++mt)
#pragma unroll
                    for (int r = 0; r < 4; ++r)
                        if (kv0 + mt * 16 + l4 * 4 + r > qrow) accs[qa][mt][r] = -1e30f;
            }

            float pmax = -1e30f;
#pragma unroll
            for (int mt = 0; mt < 4; ++mt)
#pragma unroll
                for (int r = 0; r < 4; ++r) pmax = fmaxf(pmax, accs[qa][mt][r]);
            pmax = fmaxf(pmax, __shfl_xor(pmax, 16));
            pmax = fmaxf(pmax, __shfl_xor(pmax, 32));

            // defer-rescale (THR=0, exact): only rescale when the row max grew
            if (!__all(pmax <= mrun[qa])) {
                float mnew = fmaxf(mrun[qa], pmax);
                float corr = __expf(mrun[qa] - mnew);
                lrun[qa] *= corr;
                mrun[qa] = mnew;
#pragma unroll
                for (int r = 0; r < 4; ++r) {
                    float f = __shfl(corr, l4 * 4 + r);
#pragma unroll
                    for (int nt = 0; nt < 4; ++nt) acc_o[qa][nt][r] *= f;
                }
            }

            const float m = mrun[qa];
            float sm[4];
#pragma unroll
            for (int mt = 0; mt < 4; ++mt) {
                float s = 0.f;
#pragma unroll
                for (int r = 0; r < 4; ++r) {
                    float p = __expf(accs[qa][mt][r] - m);
                    s += p;
                    pa[qa][mt >> 1][(mt & 1) * 4 + r] = (__bf16)p;   // k-slot pi mapping
                }
                sm[mt] = s;
            }
            float psum = (sm[0] + sm[1]) + (sm[2] + sm[3]);
            psum += __shfl_xor(psum, 16);
            psum += __shfl_xor(psum, 32);
            lrun[qa] += psum;
        }

        // PV with permuted k-slots: vf element j = V[kv = 32s + (j>=4?16:0) + l4*4 + (j&3)][d]
#pragma unroll
        for (int s = 0; s < 2; ++s) {
#pragma unroll
            for (int nt = 0; nt < 4; ++nt) {
                bf16x4 v0 = *(const bf16x4*)&Vs[nt * 16 + l15][s * 32 + l4 * 4];
                bf16x4 v1 = *(const bf16x4*)&Vs[nt * 16 + l15][s * 32 + 16 + l4 * 4];
                bf16x8 vf = __builtin_shufflevector(v0, v1, 0, 1, 2, 3, 4, 5, 6, 7);
                acc_o[0][nt] = __builtin_amdgcn_mfma_f32_16x16x32_bf16(pa[0][s], vf, acc_o[0][nt], 0, 0, 0);
                acc_o[1][nt] = __builtin_amdgcn_mfma_f32_16x16x32_bf16(pa[1][s], vf, acc_o[1][nt], 0, 0, 0);
            }
        }
        __syncthreads();
    }

    // finalize: divide by l, store bf16
#pragma unroll
    for (int qa = 0; qa < 2; ++qa)
#pragma unroll
        for (int r = 0; r < 4; ++r) {
            float li = __shfl(lrun[qa], l4 * 4 + r);
            float inv = 1.f / li;
            int row = qsub0 + qa * 16 + l4 * 4 + r;
#pragma unroll
            for (int nt = 0; nt < 4; ++nt)
                O[base + (size_t)row * D_ + nt * 16 + l15] = f2bf(acc_o[qa][nt][r] * inv);
        }
}

extern "C" void kernel_launch(void* const* d_in, const int* in_sizes, int n_in,
                              void* d_out, int out_size, void* d_ws, size_t ws_size,
                              hipStream_t stream) {
    const float* x  = (const float*)d_in[0];
    const float* Wq = (const float*)d_in[1];
    const float* bq = (const float*)d_in[2];
    const float* Wk = (const float*)d_in[3];
    const float* bk = (const float*)d_in[4];
    const float* Wv = (const float*)d_in[5];
    const float* bv = (const float*)d_in[6];
    const float* Wp = (const float*)d_in[7];
    const float* bp = (const float*)d_in[8];
    float* out = (float*)d_out;

    u16t* ws = (u16t*)d_ws;
    const size_t XN = (size_t)M_TOT * D_;      // 8M elems
    u16t* xb  = ws;                            // x bf16; reused as attn output O
    u16t* q   = ws + XN;
    u16t* k   = ws + 2 * XN;
    u16t* vt  = ws + 3 * XN;                   // Vt[b][h][hd][t] (written by V-GEMM epilogue)
    u16t* wtq = ws + 4 * XN;
    u16t* wtk = wtq + (size_t)D_ * D_;
    u16t* wtv = wtk + (size_t)D_ * D_;
    u16t* wtp = wtv + (size_t)D_ * D_;
    u16t* o   = xb;                            // attn output reuses xb (dead after GEMMs)

    cvt_bf16_kernel<<<(int)(XN / 8 / 256), 256, 0, stream>>>(x, xb, (int)(XN / 8));
    transp_kernel<<<dim3(16, 16, 4), 256, 0, stream>>>(Wq, Wk, Wv, Wp, wtq, wtk, wtv, wtp);

    dim3 ggrid(M_TOT / 128, D_ / 128);
    gemm_bf16_kernel<0><<<ggrid, 256, 0, stream>>>(xb, wtq, bq, q, 0.125f);
    gemm_bf16_kernel<0><<<ggrid, 256, 0, stream>>>(xb, wtk, bk, k, 1.0f);
    gemm_bf16_kernel<2><<<ggrid, 256, 0, stream>>>(xb, wtv, bv, vt, 1.0f);  // fused V-transpose

    attn_kernel<<<dim3(16, 64), 256, 0, stream>>>(q, k, vt, o);

    gemm_bf16_kernel<1><<<ggrid, 256, 0, stream>>>(o, wtp, bp, out, 1.0f);
}